// Round 4
// baseline (695.096 us; speedup 1.0000x reference)
//
#include <hip/hip_runtime.h>
#include <hip/hip_bf16.h>

#define NUM_EXPERTS 8
#define HIDDEN 2048
#define INTER 1024
#define T_TOKENS 4096
#define NSLOTS (T_TOKENS * 2)

#define BM 128
#define BN 128
#define BK 32

typedef __attribute__((ext_vector_type(8))) short short8;
typedef __attribute__((ext_vector_type(4))) float f32x4;

__device__ __forceinline__ ushort f2bf(float f) {
    __hip_bfloat16 h = __float2bfloat16(f);
    return *reinterpret_cast<ushort*>(&h);
}

__device__ __forceinline__ void load_lds16(const void* g, void* lds) {
    __builtin_amdgcn_global_load_lds(
        (const __attribute__((address_space(1))) void*)g,
        (__attribute__((address_space(3))) void*)lds, 16, 0, 0);
}

// ---------------- fp32 -> bf16 conversion ----------------
__global__ __launch_bounds__(256) void cvt_bf16(const float* __restrict__ in,
                                                ushort* __restrict__ out, int n4) {
    int i = blockIdx.x * 256 + threadIdx.x;
    int stride = gridDim.x * 256;
    for (; i < n4; i += stride) {
        float4 v = reinterpret_cast<const float4*>(in)[i];
        ushort4 o;
        o.x = f2bf(v.x); o.y = f2bf(v.y); o.z = f2bf(v.z); o.w = f2bf(v.w);
        reinterpret_cast<ushort4*>(out)[i] = o;
    }
}

// ---------------- router: logits, softmax-top2, counts ----------------
__global__ __launch_bounds__(64) void moe_router(const float* __restrict__ x,
                                                 const float* __restrict__ gw,
                                                 int* __restrict__ top_idx,
                                                 float* __restrict__ top_w,
                                                 int* __restrict__ counts) {
    int t = blockIdx.x;
    int lane = threadIdx.x;
    const float* xt = x + (size_t)t * HIDDEN;
    float acc[NUM_EXPERTS];
#pragma unroll
    for (int e = 0; e < NUM_EXPERTS; e++) acc[e] = 0.f;
    for (int h = lane; h < HIDDEN; h += 64) {
        float xv = xt[h];
#pragma unroll
        for (int e = 0; e < NUM_EXPERTS; e++)
            acc[e] = fmaf(xv, gw[e * HIDDEN + h], acc[e]);
    }
#pragma unroll
    for (int e = 0; e < NUM_EXPERTS; e++) {
#pragma unroll
        for (int off = 32; off > 0; off >>= 1)
            acc[e] += __shfl_xor(acc[e], off);
    }
    if (lane == 0) {
        int i1 = 0; float l1 = acc[0];
#pragma unroll
        for (int e = 1; e < NUM_EXPERTS; e++)
            if (acc[e] > l1) { l1 = acc[e]; i1 = e; }
        int i2 = -1; float l2 = -3.4e38f;
#pragma unroll
        for (int e = 0; e < NUM_EXPERTS; e++)
            if (e != i1 && acc[e] > l2) { l2 = acc[e]; i2 = e; }
        // renormalized top-2 of softmax == softmax over top-2 logits
        float w2 = __expf(l2 - l1);
        float denom = 1.f + w2;
        top_idx[t * 2 + 0] = i1;
        top_idx[t * 2 + 1] = i2;
        top_w[t * 2 + 0] = 1.f / denom;
        top_w[t * 2 + 1] = w2 / denom;
        atomicAdd(&counts[i1], 1);
        atomicAdd(&counts[i2], 1);
    }
}

// ---------------- offsets (exclusive scan over 8 counts) ----------------
__global__ void moe_offsets(const int* __restrict__ counts,
                            int* __restrict__ ebase, int* __restrict__ cursor) {
    if (threadIdx.x == 0 && blockIdx.x == 0) {
        int s = 0;
        for (int e = 0; e < NUM_EXPERTS; e++) {
            ebase[e] = s; cursor[e] = s; s += counts[e];
        }
    }
}

// ---------------- scatter tokens into per-expert slot lists ----------------
__global__ __launch_bounds__(256) void moe_scatter(const int* __restrict__ top_idx,
                                                   const float* __restrict__ top_w,
                                                   int* __restrict__ cursor,
                                                   int* __restrict__ slot_tok,
                                                   float* __restrict__ slot_w) {
    int t = blockIdx.x * 256 + threadIdx.x;
    if (t >= T_TOKENS) return;
#pragma unroll
    for (int k = 0; k < 2; k++) {
        int e = top_idx[t * 2 + k];
        int pos = atomicAdd(&cursor[e], 1);
        slot_tok[pos] = t;
        slot_w[pos] = top_w[t * 2 + k];
    }
}

// ---------------- fused gate/up GEMM + SwiGLU ----------------
// A = gathered tokens [cnt, H] bf16 ; B = Wg/Wu [I, H] row-major (B^T form)
__global__ __launch_bounds__(256) void moe_gateup(const ushort* __restrict__ xb,
                                                  const ushort* __restrict__ wgb,
                                                  const ushort* __restrict__ wub,
                                                  const int* __restrict__ slot_tok,
                                                  const int* __restrict__ ebase,
                                                  const int* __restrict__ ecnt,
                                                  ushort* __restrict__ act) {
    __shared__ ushort ldsA[BM * BK];
    __shared__ ushort ldsG[BN * BK];
    __shared__ ushort ldsU[BN * BK];

    const int e = blockIdx.z;
    const int bm = blockIdx.y;
    const int bn = blockIdx.x;
    const int cnt = ecnt[e];
    if (bm * BM >= cnt) return;
    const int b0 = ebase[e];

    const int tid = threadIdx.x;
    const int lane = tid & 63;
    const int wid = tid >> 6;
    const int wr = wid >> 1, wc = wid & 1;

    // staging: thread stages two 16B chunks per tile: rows (tid>>2) and +64, col (tid&3)*8
    const int ar0 = bm * BM + (tid >> 2);
    const int ar1 = ar0 + 64;
    const int cl0 = (ar0 < cnt) ? ar0 : (cnt - 1);
    const int cl1 = (ar1 < cnt) ? ar1 : (cnt - 1);
    const int tok0 = slot_tok[b0 + cl0];
    const int tok1 = slot_tok[b0 + cl1];
    const int kc = (tid & 3) * 8;
    const ushort* pA0 = xb + (size_t)tok0 * HIDDEN + kc;
    const ushort* pA1 = xb + (size_t)tok1 * HIDDEN + kc;
    const size_t wrow0 = (size_t)e * INTER + (size_t)(bn * BN + (tid >> 2));
    const ushort* pG0 = wgb + wrow0 * HIDDEN + kc;
    const ushort* pG1 = pG0 + (size_t)64 * HIDDEN;
    const ushort* pU0 = wub + wrow0 * HIDDEN + kc;
    const ushort* pU1 = pU0 + (size_t)64 * HIDDEN;

    ushort* dA = ldsA + tid * 8;  // 16 B per thread
    ushort* dG = ldsG + tid * 8;
    ushort* dU = ldsU + tid * 8;

    f32x4 accg[4][4] = {};
    f32x4 accu[4][4] = {};

    const int fr = lane & 15;
    const int fk = (lane >> 4) * 8;

    for (int kk = 0; kk < HIDDEN; kk += BK) {
        load_lds16(pA0, dA);
        load_lds16(pA1, dA + 2048);
        load_lds16(pG0, dG);
        load_lds16(pG1, dG + 2048);
        load_lds16(pU0, dU);
        load_lds16(pU1, dU + 2048);
        pA0 += BK; pA1 += BK; pG0 += BK; pG1 += BK; pU0 += BK; pU1 += BK;
        __syncthreads();

        short8 a[4], bg[4], bu[4];
#pragma unroll
        for (int m = 0; m < 4; m++)
            a[m] = *(const short8*)(ldsA + (wr * 64 + m * 16 + fr) * BK + fk);
#pragma unroll
        for (int n = 0; n < 4; n++) {
            bg[n] = *(const short8*)(ldsG + (wc * 64 + n * 16 + fr) * BK + fk);
            bu[n] = *(const short8*)(ldsU + (wc * 64 + n * 16 + fr) * BK + fk);
        }
#pragma unroll
        for (int m = 0; m < 4; m++) {
#pragma unroll
            for (int n = 0; n < 4; n++) {
                accg[m][n] = __builtin_amdgcn_mfma_f32_16x16x32_bf16(a[m], bg[n], accg[m][n], 0, 0, 0);
                accu[m][n] = __builtin_amdgcn_mfma_f32_16x16x32_bf16(a[m], bu[n], accu[m][n], 0, 0, 0);
            }
        }
        __syncthreads();
    }

    // epilogue: SwiGLU, cast bf16, store to act[slot][col]
#pragma unroll
    for (int m = 0; m < 4; m++) {
#pragma unroll
        for (int r = 0; r < 4; r++) {
            int row = bm * BM + wr * 64 + m * 16 + (lane >> 4) * 4 + r;
            if (row < cnt) {
                size_t arow = (size_t)(b0 + row) * INTER;
#pragma unroll
                for (int n = 0; n < 4; n++) {
                    int col = bn * BN + wc * 64 + n * 16 + (lane & 15);
                    float g = accg[m][n][r];
                    float u = accu[m][n][r];
                    float s = g / (1.f + __expf(-g));
                    act[arow + col] = f2bf(s * u);
                }
            }
        }
    }
}

// ---------------- down GEMM + routed atomic accumulate ----------------
// A = act[slots] [cnt, I] bf16 (contiguous) ; B = Wd [H, I] row-major
__global__ __launch_bounds__(256) void moe_down(const ushort* __restrict__ act,
                                                const ushort* __restrict__ wdb,
                                                const int* __restrict__ slot_tok,
                                                const float* __restrict__ slot_w,
                                                const int* __restrict__ ebase,
                                                const int* __restrict__ ecnt,
                                                float* __restrict__ out) {
    __shared__ ushort ldsA[BM * BK];
    __shared__ ushort ldsB[BN * BK];

    const int e = blockIdx.z;
    const int bm = blockIdx.y;
    const int bn = blockIdx.x;
    const int cnt = ecnt[e];
    if (bm * BM >= cnt) return;
    const int b0 = ebase[e];

    const int tid = threadIdx.x;
    const int lane = tid & 63;
    const int wid = tid >> 6;
    const int wr = wid >> 1, wc = wid & 1;

    const int ar0 = bm * BM + (tid >> 2);
    const int ar1 = ar0 + 64;
    const int sr0 = b0 + ((ar0 < cnt) ? ar0 : (cnt - 1));
    const int sr1 = b0 + ((ar1 < cnt) ? ar1 : (cnt - 1));
    const int kc = (tid & 3) * 8;
    const ushort* pA0 = act + (size_t)sr0 * INTER + kc;
    const ushort* pA1 = act + (size_t)sr1 * INTER + kc;
    const size_t wrow = (size_t)e * HIDDEN + (size_t)(bn * BN + (tid >> 2));
    const ushort* pB0 = wdb + wrow * INTER + kc;
    const ushort* pB1 = pB0 + (size_t)64 * INTER;

    ushort* dA = ldsA + tid * 8;
    ushort* dB = ldsB + tid * 8;

    f32x4 acc[4][4] = {};

    const int fr = lane & 15;
    const int fk = (lane >> 4) * 8;

    for (int kk = 0; kk < INTER; kk += BK) {
        load_lds16(pA0, dA);
        load_lds16(pA1, dA + 2048);
        load_lds16(pB0, dB);
        load_lds16(pB1, dB + 2048);
        pA0 += BK; pA1 += BK; pB0 += BK; pB1 += BK;
        __syncthreads();

        short8 a[4], b[4];
#pragma unroll
        for (int m = 0; m < 4; m++)
            a[m] = *(const short8*)(ldsA + (wr * 64 + m * 16 + fr) * BK + fk);
#pragma unroll
        for (int n = 0; n < 4; n++)
            b[n] = *(const short8*)(ldsB + (wc * 64 + n * 16 + fr) * BK + fk);
#pragma unroll
        for (int m = 0; m < 4; m++) {
#pragma unroll
            for (int n = 0; n < 4; n++) {
                acc[m][n] = __builtin_amdgcn_mfma_f32_16x16x32_bf16(a[m], b[n], acc[m][n], 0, 0, 0);
            }
        }
        __syncthreads();
    }

#pragma unroll
    for (int m = 0; m < 4; m++) {
#pragma unroll
        for (int r = 0; r < 4; r++) {
            int row = bm * BM + wr * 64 + m * 16 + (lane >> 4) * 4 + r;
            if (row < cnt) {
                int slot = b0 + row;
                int tok = slot_tok[slot];
                float w = slot_w[slot];
                float* orow = out + (size_t)tok * HIDDEN;
#pragma unroll
                for (int n = 0; n < 4; n++) {
                    int col = bn * BN + wc * 64 + n * 16 + (lane & 15);
                    atomicAdd(&orow[col], acc[m][n][r] * w);
                }
            }
        }
    }
}

// ---------------- launch ----------------
extern "C" void kernel_launch(void* const* d_in, const int* in_sizes, int n_in,
                              void* d_out, int out_size, void* d_ws, size_t ws_size,
                              hipStream_t stream) {
    const float* x  = (const float*)d_in[0];
    const float* gw = (const float*)d_in[1];
    const float* wg = (const float*)d_in[2];
    const float* wu = (const float*)d_in[3];
    const float* wd = (const float*)d_in[4];
    float* out = (float*)d_out;

    char* ws = (char*)d_ws;
    // layout (bytes)
    ushort* xb  = (ushort*)(ws);                                   // 16 MB
    ushort* wgb = (ushort*)(ws + 16777216);                        // 32 MB
    ushort* wub = (ushort*)(ws + 16777216 + 33554432);             // 32 MB
    ushort* wdb = (ushort*)(ws + 16777216 + 2u * 33554432);        // 32 MB
    ushort* act = (ushort*)(ws + 16777216 + 3u * 33554432);        // 16 MB
    char* p = ws + 2u * 16777216 + 3u * 33554432;
    int*   top_idx  = (int*)p;   p += 32768;
    float* top_w    = (float*)p; p += 32768;
    int*   slot_tok = (int*)p;   p += 32768;
    float* slot_w   = (float*)p; p += 32768;
    int*   counts   = (int*)p;   p += 128;
    int*   ebase    = (int*)p;   p += 128;
    int*   cursor   = (int*)p;   p += 128;

    hipMemsetAsync(counts, 0, 128, stream);
    hipMemsetAsync(d_out, 0, (size_t)out_size * sizeof(float), stream);

    cvt_bf16<<<1024, 256, 0, stream>>>(x,  xb,  (T_TOKENS * HIDDEN) / 4);
    cvt_bf16<<<1024, 256, 0, stream>>>(wg, wgb, (NUM_EXPERTS * INTER * HIDDEN) / 4);
    cvt_bf16<<<1024, 256, 0, stream>>>(wu, wub, (NUM_EXPERTS * INTER * HIDDEN) / 4);
    cvt_bf16<<<1024, 256, 0, stream>>>(wd, wdb, (NUM_EXPERTS * HIDDEN * INTER) / 4);

    moe_router<<<T_TOKENS, 64, 0, stream>>>(x, gw, top_idx, top_w, counts);
    moe_offsets<<<1, 64, 0, stream>>>(counts, ebase, cursor);
    moe_scatter<<<(T_TOKENS + 255) / 256, 256, 0, stream>>>(top_idx, top_w, cursor, slot_tok, slot_w);

    moe_gateup<<<dim3(INTER / BN, T_TOKENS / BM, NUM_EXPERTS), 256, 0, stream>>>(
        xb, wgb, wub, slot_tok, ebase, counts, act);
    moe_down<<<dim3(HIDDEN / BN, T_TOKENS / BM, NUM_EXPERTS), 256, 0, stream>>>(
        act, wdb, slot_tok, slot_w, ebase, counts, out);
}

// Round 5
// 616.935 us; speedup vs baseline: 1.1267x; 1.1267x over previous
//
#include <hip/hip_runtime.h>
#include <hip/hip_bf16.h>

#define NUM_EXPERTS 8
#define HIDDEN 2048
#define INTER 1024
#define T_TOKENS 4096

#define BK 32
#define GU_BM 64
#define GU_BN 128
#define DN_BM 64
#define DN_BN 128

typedef __attribute__((ext_vector_type(8))) short short8;
typedef __attribute__((ext_vector_type(4))) float f32x4;

__device__ __forceinline__ ushort f2bf(float f) {
    __hip_bfloat16 h = __float2bfloat16(f);
    return *reinterpret_cast<ushort*>(&h);
}

__device__ __forceinline__ void load_lds16(const void* g, void* lds) {
    __builtin_amdgcn_global_load_lds(
        (const __attribute__((address_space(1))) void*)g,
        (__attribute__((address_space(3))) void*)lds, 16, 0, 0);
}

// ---------------- fp32 -> bf16 conversion ----------------
__global__ __launch_bounds__(256) void cvt_bf16(const float* __restrict__ in,
                                                ushort* __restrict__ out, int n4) {
    int i = blockIdx.x * 256 + threadIdx.x;
    int stride = gridDim.x * 256;
    for (; i < n4; i += stride) {
        float4 v = reinterpret_cast<const float4*>(in)[i];
        ushort4 o;
        o.x = f2bf(v.x); o.y = f2bf(v.y); o.z = f2bf(v.z); o.w = f2bf(v.w);
        reinterpret_cast<ushort4*>(out)[i] = o;
    }
}

// ---------------- router: logits, softmax-top2, counts ----------------
__global__ __launch_bounds__(64) void moe_router(const float* __restrict__ x,
                                                 const float* __restrict__ gw,
                                                 int* __restrict__ top_idx,
                                                 float* __restrict__ top_w,
                                                 int* __restrict__ counts) {
    int t = blockIdx.x;
    int lane = threadIdx.x;
    const float* xt = x + (size_t)t * HIDDEN;
    float acc[NUM_EXPERTS];
#pragma unroll
    for (int e = 0; e < NUM_EXPERTS; e++) acc[e] = 0.f;
    for (int h = lane; h < HIDDEN; h += 64) {
        float xv = xt[h];
#pragma unroll
        for (int e = 0; e < NUM_EXPERTS; e++)
            acc[e] = fmaf(xv, gw[e * HIDDEN + h], acc[e]);
    }
#pragma unroll
    for (int e = 0; e < NUM_EXPERTS; e++) {
#pragma unroll
        for (int off = 32; off > 0; off >>= 1)
            acc[e] += __shfl_xor(acc[e], off);
    }
    if (lane == 0) {
        int i1 = 0; float l1 = acc[0];
#pragma unroll
        for (int e = 1; e < NUM_EXPERTS; e++)
            if (acc[e] > l1) { l1 = acc[e]; i1 = e; }
        int i2 = -1; float l2 = -3.4e38f;
#pragma unroll
        for (int e = 0; e < NUM_EXPERTS; e++)
            if (e != i1 && acc[e] > l2) { l2 = acc[e]; i2 = e; }
        float w2 = __expf(l2 - l1);
        float denom = 1.f + w2;
        top_idx[t * 2 + 0] = i1;
        top_idx[t * 2 + 1] = i2;
        top_w[t * 2 + 0] = 1.f / denom;
        top_w[t * 2 + 1] = w2 / denom;
        atomicAdd(&counts[i1], 1);
        atomicAdd(&counts[i2], 1);
    }
}

// ---------------- offsets ----------------
__global__ void moe_offsets(const int* __restrict__ counts,
                            int* __restrict__ ebase, int* __restrict__ cursor) {
    if (threadIdx.x == 0 && blockIdx.x == 0) {
        int s = 0;
        for (int e = 0; e < NUM_EXPERTS; e++) {
            ebase[e] = s; cursor[e] = s; s += counts[e];
        }
    }
}

// ---------------- scatter ----------------
__global__ __launch_bounds__(256) void moe_scatter(const int* __restrict__ top_idx,
                                                   const float* __restrict__ top_w,
                                                   int* __restrict__ cursor,
                                                   int* __restrict__ slot_tok,
                                                   float* __restrict__ slot_w) {
    int t = blockIdx.x * 256 + threadIdx.x;
    if (t >= T_TOKENS) return;
#pragma unroll
    for (int k = 0; k < 2; k++) {
        int e = top_idx[t * 2 + k];
        int pos = atomicAdd(&cursor[e], 1);
        slot_tok[pos] = t;
        slot_w[pos] = top_w[t * 2 + k];
    }
}

// ---------------- fused gate/up GEMM + SwiGLU ----------------
// 64x128 tile, 2-phase double-buffered pipeline, XOR bank-swizzle via
// pre-swizzled global source (global_load_lds writes LDS linearly).
__global__ __launch_bounds__(256, 3) void moe_gateup(const ushort* __restrict__ xb,
                                                     const ushort* __restrict__ wgb,
                                                     const ushort* __restrict__ wub,
                                                     const int* __restrict__ slot_tok,
                                                     const int* __restrict__ ebase,
                                                     const int* __restrict__ ecnt,
                                                     ushort* __restrict__ act) {
    __shared__ ushort ldsA[2][GU_BM * BK];   // 2 x 4 KB
    __shared__ ushort ldsG[2][GU_BN * BK];   // 2 x 8 KB
    __shared__ ushort ldsU[2][GU_BN * BK];   // 2 x 8 KB

    const int e = blockIdx.z;
    const int bm = blockIdx.y;
    const int bn = blockIdx.x;
    const int cnt = ecnt[e];
    if (bm * GU_BM >= cnt) return;
    const int b0 = ebase[e];

    const int tid = threadIdx.x;
    const int lane = tid & 63;
    const int wid = tid >> 6;
    const int wr = wid >> 1, wc = wid & 1;   // wave 2x2: 32 rows x 64 cols

    // ---- staging sources (col pre-swizzled: slot cs holds logical chunk cs^s(r)) ----
    const int r = tid >> 2, cs = tid & 3;
    const int scl = (cs ^ ((r >> 1) & 3)) * 8;            // element offset within row
    const int ar = bm * GU_BM + r;
    const int tok = slot_tok[b0 + ((ar < cnt) ? ar : (cnt - 1))];
    const ushort* pA = xb + (size_t)tok * HIDDEN + scl;
    const size_t wrow0 = (size_t)e * INTER + (size_t)(bn * GU_BN + r);
    const ushort* pG0 = wgb + wrow0 * HIDDEN + scl;
    const ushort* pG1 = pG0 + (size_t)64 * HIDDEN;        // s(r+64)==s(r)
    const ushort* pU0 = wub + wrow0 * HIDDEN + scl;
    const ushort* pU1 = pU0 + (size_t)64 * HIDDEN;

    // ---- fragment read constants ----
    const int fr = lane & 15;
    // all row bases (wr*32, wc*64, m*16, n*16) are 0 mod 8, so swizzle bits
    // depend only on fr: colsw = (cb ^ ((R>>1)&3)) * 8 with cb = lane>>4
    const int colsw = (((lane >> 4) ^ ((fr >> 1) & 3)) * 8);

    f32x4 accg[2][4] = {};
    f32x4 accu[2][4] = {};

#define GU_STAGE(buf, t)                                              \
    do {                                                              \
        const int _o = (t) * BK;                                      \
        load_lds16(pA + _o,  &ldsA[buf][tid * 8]);                    \
        load_lds16(pG0 + _o, &ldsG[buf][tid * 8]);                    \
        load_lds16(pG1 + _o, &ldsG[buf][2048 + tid * 8]);             \
        load_lds16(pU0 + _o, &ldsU[buf][tid * 8]);                    \
        load_lds16(pU1 + _o, &ldsU[buf][2048 + tid * 8]);             \
    } while (0)

    GU_STAGE(0, 0);
    __syncthreads();

    int cur = 0;
    const int NT = HIDDEN / BK;   // 64
    for (int t = 0; t < NT; ++t) {
        if (t + 1 < NT) GU_STAGE(cur ^ 1, t + 1);   // prefetch overlaps MFMA below

        const ushort* LA = ldsA[cur];
        const ushort* LG = ldsG[cur];
        const ushort* LU = ldsU[cur];
        short8 a[2], bg[4], bu[4];
#pragma unroll
        for (int m = 0; m < 2; m++)
            a[m] = *(const short8*)(LA + (wr * 32 + m * 16 + fr) * BK + colsw);
#pragma unroll
        for (int n = 0; n < 4; n++) {
            bg[n] = *(const short8*)(LG + (wc * 64 + n * 16 + fr) * BK + colsw);
            bu[n] = *(const short8*)(LU + (wc * 64 + n * 16 + fr) * BK + colsw);
        }
#pragma unroll
        for (int m = 0; m < 2; m++) {
#pragma unroll
            for (int n = 0; n < 4; n++) {
                accg[m][n] = __builtin_amdgcn_mfma_f32_16x16x32_bf16(a[m], bg[n], accg[m][n], 0, 0, 0);
                accu[m][n] = __builtin_amdgcn_mfma_f32_16x16x32_bf16(a[m], bu[n], accu[m][n], 0, 0, 0);
            }
        }
        __syncthreads();   // drains prefetch (vmcnt) + guards buffer reuse
        cur ^= 1;
    }
#undef GU_STAGE

    // epilogue: SwiGLU, cast bf16, store act[slot][col]
#pragma unroll
    for (int m = 0; m < 2; m++) {
#pragma unroll
        for (int rr = 0; rr < 4; rr++) {
            int row = bm * GU_BM + wr * 32 + m * 16 + (lane >> 4) * 4 + rr;
            if (row < cnt) {
                size_t arow = (size_t)(b0 + row) * INTER;
#pragma unroll
                for (int n = 0; n < 4; n++) {
                    int col = bn * GU_BN + wc * 64 + n * 16 + fr;
                    float g = accg[m][n][rr];
                    float u = accu[m][n][rr];
                    float s = g / (1.f + __expf(-g));
                    act[arow + col] = f2bf(s * u);
                }
            }
        }
    }
}

// ---------------- down GEMM + routed atomic accumulate ----------------
__global__ __launch_bounds__(256, 4) void moe_down(const ushort* __restrict__ act,
                                                   const ushort* __restrict__ wdb,
                                                   const int* __restrict__ slot_tok,
                                                   const float* __restrict__ slot_w,
                                                   const int* __restrict__ ebase,
                                                   const int* __restrict__ ecnt,
                                                   float* __restrict__ out) {
    __shared__ ushort ldsA[2][DN_BM * BK];   // 2 x 4 KB
    __shared__ ushort ldsB[2][DN_BN * BK];   // 2 x 8 KB

    const int e = blockIdx.z;
    const int bm = blockIdx.y;
    const int bn = blockIdx.x;
    const int cnt = ecnt[e];
    if (bm * DN_BM >= cnt) return;
    const int b0 = ebase[e];

    const int tid = threadIdx.x;
    const int lane = tid & 63;
    const int wid = tid >> 6;
    const int wr = wid >> 1, wc = wid & 1;

    const int r = tid >> 2, cs = tid & 3;
    const int scl = (cs ^ ((r >> 1) & 3)) * 8;
    const int ar = bm * DN_BM + r;
    const int sr = b0 + ((ar < cnt) ? ar : (cnt - 1));
    const ushort* pA = act + (size_t)sr * INTER + scl;
    const size_t wrow = (size_t)e * HIDDEN + (size_t)(bn * DN_BN + r);
    const ushort* pB0 = wdb + wrow * INTER + scl;
    const ushort* pB1 = pB0 + (size_t)64 * INTER;

    const int fr = lane & 15;
    const int colsw = (((lane >> 4) ^ ((fr >> 1) & 3)) * 8);

    f32x4 acc[2][4] = {};

#define DN_STAGE(buf, t)                                              \
    do {                                                              \
        const int _o = (t) * BK;                                      \
        load_lds16(pA + _o,  &ldsA[buf][tid * 8]);                    \
        load_lds16(pB0 + _o, &ldsB[buf][tid * 8]);                    \
        load_lds16(pB1 + _o, &ldsB[buf][2048 + tid * 8]);             \
    } while (0)

    DN_STAGE(0, 0);
    __syncthreads();

    int cur = 0;
    const int NT = INTER / BK;   // 32
    for (int t = 0; t < NT; ++t) {
        if (t + 1 < NT) DN_STAGE(cur ^ 1, t + 1);

        const ushort* LA = ldsA[cur];
        const ushort* LB = ldsB[cur];
        short8 a[2], b[4];
#pragma unroll
        for (int m = 0; m < 2; m++)
            a[m] = *(const short8*)(LA + (wr * 32 + m * 16 + fr) * BK + colsw);
#pragma unroll
        for (int n = 0; n < 4; n++)
            b[n] = *(const short8*)(LB + (wc * 64 + n * 16 + fr) * BK + colsw);
#pragma unroll
        for (int m = 0; m < 2; m++) {
#pragma unroll
            for (int n = 0; n < 4; n++)
                acc[m][n] = __builtin_amdgcn_mfma_f32_16x16x32_bf16(a[m], b[n], acc[m][n], 0, 0, 0);
        }
        __syncthreads();
        cur ^= 1;
    }
#undef DN_STAGE

#pragma unroll
    for (int m = 0; m < 2; m++) {
#pragma unroll
        for (int rr = 0; rr < 4; rr++) {
            int row = bm * DN_BM + wr * 32 + m * 16 + (lane >> 4) * 4 + rr;
            if (row < cnt) {
                int slot = b0 + row;
                int tok = slot_tok[slot];
                float w = slot_w[slot];
                float* orow = out + (size_t)tok * HIDDEN;
#pragma unroll
                for (int n = 0; n < 4; n++) {
                    int col = bn * DN_BN + wc * 64 + n * 16 + fr;
                    atomicAdd(&orow[col], acc[m][n][rr] * w);
                }
            }
        }
    }
}

// ---------------- launch ----------------
extern "C" void kernel_launch(void* const* d_in, const int* in_sizes, int n_in,
                              void* d_out, int out_size, void* d_ws, size_t ws_size,
                              hipStream_t stream) {
    const float* x  = (const float*)d_in[0];
    const float* gw = (const float*)d_in[1];
    const float* wg = (const float*)d_in[2];
    const float* wu = (const float*)d_in[3];
    const float* wd = (const float*)d_in[4];
    float* out = (float*)d_out;

    char* ws = (char*)d_ws;
    ushort* xb  = (ushort*)(ws);                                   // 16 MB
    ushort* wgb = (ushort*)(ws + 16777216);                        // 32 MB
    ushort* wub = (ushort*)(ws + 16777216 + 33554432);             // 32 MB
    ushort* wdb = (ushort*)(ws + 16777216 + 2u * 33554432);        // 32 MB
    ushort* act = (ushort*)(ws + 16777216 + 3u * 33554432);        // 16 MB
    char* p = ws + 2u * 16777216 + 3u * 33554432;
    int*   top_idx  = (int*)p;   p += 32768;
    float* top_w    = (float*)p; p += 32768;
    int*   slot_tok = (int*)p;   p += 32768;
    float* slot_w   = (float*)p; p += 32768;
    int*   counts   = (int*)p;   p += 128;
    int*   ebase    = (int*)p;   p += 128;
    int*   cursor   = (int*)p;   p += 128;

    hipMemsetAsync(counts, 0, 128, stream);
    hipMemsetAsync(d_out, 0, (size_t)out_size * sizeof(float), stream);

    cvt_bf16<<<1024, 256, 0, stream>>>(x,  xb,  (T_TOKENS * HIDDEN) / 4);
    cvt_bf16<<<1024, 256, 0, stream>>>(wg, wgb, (NUM_EXPERTS * INTER * HIDDEN) / 4);
    cvt_bf16<<<1024, 256, 0, stream>>>(wu, wub, (NUM_EXPERTS * INTER * HIDDEN) / 4);
    cvt_bf16<<<1024, 256, 0, stream>>>(wd, wdb, (NUM_EXPERTS * HIDDEN * INTER) / 4);

    moe_router<<<T_TOKENS, 64, 0, stream>>>(x, gw, top_idx, top_w, counts);
    moe_offsets<<<1, 64, 0, stream>>>(counts, ebase, cursor);
    moe_scatter<<<(T_TOKENS + 255) / 256, 256, 0, stream>>>(top_idx, top_w, cursor, slot_tok, slot_w);

    moe_gateup<<<dim3(INTER / GU_BN, T_TOKENS / GU_BM, NUM_EXPERTS), 256, 0, stream>>>(
        xb, wgb, wub, slot_tok, ebase, counts, act);
    moe_down<<<dim3(HIDDEN / DN_BN, T_TOKENS / DN_BM, NUM_EXPERTS), 256, 0, stream>>>(
        act, wdb, slot_tok, slot_w, ebase, counts, out);
}